// Round 7
// baseline (1986.893 us; speedup 1.0000x reference)
//
#include <hip/hip_runtime.h>
#include <math.h>

#define BN_SF 0.9999950000374997f  /* 1/sqrt(1+1e-5) */

typedef __attribute__((ext_vector_type(8))) short short8v;
typedef __attribute__((ext_vector_type(4))) float float4v;

__device__ __forceinline__ float sigm(float x) { return 1.0f / (1.0f + expf(-x)); }

__device__ __forceinline__ short f2bf(float x) {
    unsigned u = __builtin_bit_cast(unsigned, x);
    unsigned r = (u + 0x7fffu + ((u >> 16) & 1u)) >> 16;
    return (short)r;
}
__device__ __forceinline__ float bf2f(short h) {
    unsigned u = ((unsigned)(unsigned short)h) << 16;
    return __builtin_bit_cast(float, u);
}

// f32 [K][N] row-major -> bf16 B-fragment layout for mfma_f32_16x16x32_bf16
template <int K, int N>
__device__ __forceinline__ void cvtB(const float* __restrict__ src, short* __restrict__ dst,
                                     float scale, int i) {
    int k = i / N, n = i % N;
    size_t d = (size_t)(n >> 4) * (K >> 5) * 512 + (size_t)(k >> 5) * 512
             + (size_t)(((n & 15) + (((k & 31) >> 3) << 4)) << 3) + (k & 7);
    dst[d] = f2bf(scale * src[i]);
}

struct SetupP {
    const float *Wm2, *Wd1, *Wd2, *Wm1, *Wih, *Whh, *Wpat, *bpat, *bm1;
    short *Wm2s, *Wd1f, *Wd2f, *Wm1f, *WgHi, *WgLo;
    float *uv;
};

__global__ __launch_bounds__(256) void k_setup(SetupP p) {
    int gt = blockIdx.x * 256 + threadIdx.x;
    int stride = gridDim.x * 256;
    for (int i = gt; i < 512 * 1024; i += stride)  cvtB<512, 1024>(p.Wm2, p.Wm2s, 1.f, i);
    for (int i = gt; i < 1152 * 1024; i += stride) cvtB<1152, 1024>(p.Wd1, p.Wd1f, 1.f, i);
    for (int i = gt; i < 1024 * 128; i += stride)  cvtB<1024, 128>(p.Wd2, p.Wd2f, 1.f, i);
    for (int i = gt; i < 128 * 512; i += stride)   cvtB<128, 512>(p.Wm1, p.Wm1f, 0.05f, i);
    for (int i = gt; i < 192 * 512; i += stride) {  // [W_ih;W_hh] hi/lo split
        int k = i >> 9, n = i & 511;
        float v = (k < 64) ? p.Wih[k * 512 + n] : p.Whh[(k - 64) * 512 + n];
        short hi = f2bf(v), lo = f2bf(v - bf2f(hi));
        size_t d = (size_t)(n >> 4) * 3072 + (size_t)(k >> 5) * 512
                 + (size_t)(((n & 15) + (((k & 31) >> 3) << 4)) << 3) + (k & 7);
        p.WgHi[d] = hi; p.WgLo[d] = lo;
    }
    if (blockIdx.x == 0) {  // uv: rank-1 agent-type folding (0.05 folded into u,v)
        __shared__ float rw[64];
        int t = threadIdx.x;
        if (t < 64) { float s = 0.f; for (int k = 0; k < 6; ++k) s += p.Wpat[k * 64 + t]; rw[t] = s; }
        __syncthreads();
        for (int c = t; c < 512; c += 256) {
            float u = 0.f, v = 0.f;
            for (int e = 0; e < 64; ++e) {
                float wg = p.Wm1[(128 + e) * 512 + c];
                u += rw[e] * wg; v += p.bpat[e] * wg;
            }
            p.uv[c] = 0.05f * u; p.uv[512 + c] = 0.05f * v + p.bm1[c];
        }
    }
}

struct MainP {
    const float *lpr, *h0, *c0, *at0;
    const float *Wsp, *bsp, *bih, *bhh, *Whp, *bhp;
    const float *bm2, *bd1, *bd2, *uv;
    const short *Wm2s, *Wd1f, *Wd2f, *Wm1f, *WgHi, *WgLo;
    float *out;
};

// 32 blocks (1 scene each) x 1024 threads (16 waves). All 12 steps in-block.
// launch_bounds(1024,4): 4 waves/SIMD min -> up to 128 VGPR so batched loads
// stay in registers and the scheduler can pipeline loads across rounds.
__global__ __launch_bounds__(1024, 4) void k_main(MainP p) {
    __shared__ short uni[16384];     // 32 KB: XFH/XFL | M1F (time-multiplexed)
    __shared__ short dh1f[32768];    // 64 KB: dh1 A-frags [mt2][kc32][512]
    __shared__ float shF[32][132];   // h_new f32 (padded)
    __shared__ short xmf[4096];      // h_new A-frags [mt2][kc4][512]
    __shared__ short sphb[1024];     // ph bf16, linear k order
    __shared__ float srel[64];
    __shared__ float sat[32];

    const int t = threadIdx.x, s = blockIdx.x;
    const int l = t & 63, w = t >> 6;
    const int mt = w >> 3, w8 = w & 7;
    const int colb = w8 * 16 + (l & 15);
    const int rbase = (l >> 4) << 2;

#define XFH(m) (uni + (m) * 3072)
#define XFL(m) (uni + 6144 + (m) * 3072)
#define M1F(m) (uni + (m) * 8192)

    if (t < 32) sat[t] = p.at0[s * 32 + t];
    float cr[4];
#pragma unroll
    for (int r = 0; r < 4; ++r)
        cr[r] = p.c0[(s * 32 + mt * 16 + rbase + r) * 128 + colb];

    // di0 = lpr @ Wsp + bsp -> xf kc0..1 (hi/lo)
    for (int i = t; i < 2048; i += 1024) {
        int row = i >> 6, c = i & 63;
        float dv = p.lpr[(s * 32 + row) * 2] * p.Wsp[c]
                 + p.lpr[(s * 32 + row) * 2 + 1] * p.Wsp[64 + c] + p.bsp[c];
        short hi = f2bf(dv);
        int off = (c >> 5) * 512 + ((row & 15) + (((c & 31) >> 3) << 4)) * 8 + (c & 7);
        XFH(row >> 4)[off] = hi; XFL(row >> 4)[off] = f2bf(dv - bf2f(hi));
    }

    for (int st = 0; st < 12; ++st) {
        // ---- P0: h_in (h0 or dh2 of prev dh1) -> xf kc2..5 hi/lo ----
        if (st == 0) {
            for (int i = t; i < 4096; i += 1024) {
                int m2 = i >> 11, pos = i & 2047;
                int kc = pos >> 9, ll = (pos >> 3) & 63, j = pos & 7;
                int row = m2 * 16 + (ll & 15), kh = kc * 32 + ((ll >> 4) << 3) + j;
                float v = p.h0[(s * 32 + row) * 128 + kh];
                short hi = f2bf(v);
                XFH(m2)[(kc + 2) * 512 + ll * 8 + j] = hi;
                XFL(m2)[(kc + 2) * 512 + ll * 8 + j] = f2bf(v - bf2f(hi));
            }
        } else {
            float4v hacc = {0.f, 0.f, 0.f, 0.f};
            const short* ap = dh1f + mt * 16384 + l * 8;
            const short* bp = p.Wd2f + (size_t)w8 * 16384 + l * 8;
#pragma unroll
            for (int kt = 0; kt < 4; ++kt) {
                short8v B[8], A[8];
#pragma unroll
                for (int kk = 0; kk < 8; ++kk)
                    B[kk] = *(const short8v*)(bp + (kt * 8 + kk) * 512);
#pragma unroll
                for (int kk = 0; kk < 8; ++kk)
                    A[kk] = *(const short8v*)(ap + (kt * 8 + kk) * 512);
#pragma unroll
                for (int kk = 0; kk < 8; ++kk)
                    hacc = __builtin_amdgcn_mfma_f32_16x16x32_bf16(A[kk], B[kk], hacc, 0, 0, 0);
            }
            int kx = 64 + colb, kcx = kx >> 5, jx = kx & 7, lxb = ((kx & 31) >> 3) << 4;
            float bb2 = p.bd2[colb];
#pragma unroll
            for (int r = 0; r < 4; ++r) {
                float hn = fmaxf(BN_SF * (hacc[r] + bb2), 0.f);
                short hi = f2bf(hn);
                int off = kcx * 512 + (rbase + r + lxb) * 8 + jx;
                XFH(mt)[off] = hi; XFL(mt)[off] = f2bf(hn - bf2f(hi));
            }
        }
        __syncthreads();  // S1

        // ---- P1: gates (3-term hi/lo MFMA) + LSTM pointwise ----
        {
            float4v ga[4] = {{0,0,0,0},{0,0,0,0},{0,0,0,0},{0,0,0,0}};
#pragma unroll
            for (int kt = 0; kt < 3; ++kt) {
                short8v BH[2][4], BL[2][4], AH[2], AL[2];
#pragma unroll
                for (int kk = 0; kk < 2; ++kk) {
                    int kc = kt * 2 + kk;
#pragma unroll
                    for (int q = 0; q < 4; ++q) {
                        int nf = w8 + 8 * q;
                        BH[kk][q] = *(const short8v*)(p.WgHi + (size_t)nf * 3072 + kc * 512 + l * 8);
                        BL[kk][q] = *(const short8v*)(p.WgLo + (size_t)nf * 3072 + kc * 512 + l * 8);
                    }
                    AH[kk] = *(const short8v*)(XFH(mt) + kc * 512 + l * 8);
                    AL[kk] = *(const short8v*)(XFL(mt) + kc * 512 + l * 8);
                }
#pragma unroll
                for (int kk = 0; kk < 2; ++kk)
#pragma unroll
                    for (int q = 0; q < 4; ++q) {
                        ga[q] = __builtin_amdgcn_mfma_f32_16x16x32_bf16(AH[kk], BH[kk][q], ga[q], 0, 0, 0);
                        ga[q] = __builtin_amdgcn_mfma_f32_16x16x32_bf16(AH[kk], BL[kk][q], ga[q], 0, 0, 0);
                        ga[q] = __builtin_amdgcn_mfma_f32_16x16x32_bf16(AL[kk], BH[kk][q], ga[q], 0, 0, 0);
                    }
            }
            float bI = p.bih[colb]       + p.bhh[colb];
            float bF = p.bih[colb + 128] + p.bhh[colb + 128];
            float bG = p.bih[colb + 256] + p.bhh[colb + 256];
            float bO = p.bih[colb + 384] + p.bhh[colb + 384];
            int kcm = colb >> 5, jm = colb & 7, lmb = ((colb & 31) >> 3) << 4;
#pragma unroll
            for (int r = 0; r < 4; ++r) {
                int row = mt * 16 + rbase + r;
                float cn = sigm(ga[1][r] + bF) * cr[r] + sigm(ga[0][r] + bI) * tanhf(ga[2][r] + bG);
                cr[r] = cn;
                float hn = sigm(ga[3][r] + bO) * tanhf(cn);
                shF[row][colb] = hn;
                xmf[mt * 2048 + kcm * 512 + (rbase + r + lmb) * 8 + jm] = f2bf(hn);
            }
        }
        __syncthreads();  // S2

        // ---- P2: rel (f32, exact -> out) + m1 MFMA -> M1F ----
        if (t < 512) {
            int row = t >> 4, d = (t >> 3) & 1, seg = t & 7;
            float v = 0.f;
#pragma unroll
            for (int kk = 0; kk < 16; ++kk) {
                int k = seg * 16 + kk;
                v += shF[row][k] * p.Whp[k * 2 + d];
            }
            v += __shfl_xor(v, 1, 64); v += __shfl_xor(v, 2, 64); v += __shfl_xor(v, 4, 64);
            if (seg == 0) {
                v += p.bhp[d];
                srel[row * 2 + d] = v;
                p.out[(size_t)st * 2048 + (s * 32 + row) * 2 + d] = v;
            }
        }
        {
            float4v ma[4] = {{0,0,0,0},{0,0,0,0},{0,0,0,0},{0,0,0,0}};
            short8v A[4], B[4][4];
#pragma unroll
            for (int kc = 0; kc < 4; ++kc) {
#pragma unroll
                for (int q = 0; q < 4; ++q)
                    B[kc][q] = *(const short8v*)(p.Wm1f + (size_t)(w8 * 4 + q) * 2048 + kc * 512 + l * 8);
                A[kc] = *(const short8v*)(xmf + mt * 2048 + kc * 512 + l * 8);
            }
#pragma unroll
            for (int kc = 0; kc < 4; ++kc)
#pragma unroll
                for (int q = 0; q < 4; ++q)
                    ma[q] = __builtin_amdgcn_mfma_f32_16x16x32_bf16(A[kc], B[kc][q], ma[q], 0, 0, 0);
#pragma unroll
            for (int q = 0; q < 4; ++q) {
                int col = (w8 * 4 + q) * 16 + (l & 15);
                float uc = p.uv[col], vc = p.uv[512 + col];
                int kcA = col >> 5, jA = col & 7, lA = ((col & 31) >> 3) << 4;
#pragma unroll
                for (int r = 0; r < 4; ++r) {
                    int rowC = mt * 16 + rbase + r;
                    float m1v = fmaxf(BN_SF * (ma[q][r] + sat[rowC] * uc + vc), 0.f);
                    M1F(mt)[kcA * 512 + (rbase + r + lA) * 8 + jA] = f2bf(m1v);
                }
            }
        }
        __syncthreads();  // S3

        // ---- P3: m2 MFMA + per-scene colmax -> sphb ----
        {
            float4v acc2[2][4] = {{{0,0,0,0},{0,0,0,0},{0,0,0,0},{0,0,0,0}},
                                  {{0,0,0,0},{0,0,0,0},{0,0,0,0},{0,0,0,0}}};
            const short* a0p = M1F(0) + l * 8;
            const short* a1p = M1F(1) + l * 8;
            const short* bp = p.Wm2s + (size_t)(w * 4) * 8192 + l * 8;
#pragma unroll
            for (int kt = 0; kt < 8; ++kt) {
                short8v A0[2], A1[2], B[2][4];
#pragma unroll
                for (int kk = 0; kk < 2; ++kk) {
                    int kc = kt * 2 + kk;
#pragma unroll
                    for (int q = 0; q < 4; ++q)
                        B[kk][q] = *(const short8v*)(bp + q * 8192 + kc * 512);
                    A0[kk] = *(const short8v*)(a0p + kc * 512);
                    A1[kk] = *(const short8v*)(a1p + kc * 512);
                }
#pragma unroll
                for (int kk = 0; kk < 2; ++kk)
#pragma unroll
                    for (int q = 0; q < 4; ++q) {
                        acc2[0][q] = __builtin_amdgcn_mfma_f32_16x16x32_bf16(A0[kk], B[kk][q], acc2[0][q], 0, 0, 0);
                        acc2[1][q] = __builtin_amdgcn_mfma_f32_16x16x32_bf16(A1[kk], B[kk][q], acc2[1][q], 0, 0, 0);
                    }
            }
#pragma unroll
            for (int q = 0; q < 4; ++q) {
                float m = acc2[0][q][0];
#pragma unroll
                for (int ri = 1; ri < 4; ++ri) m = fmaxf(m, acc2[0][q][ri]);
#pragma unroll
                for (int ri = 0; ri < 4; ++ri) m = fmaxf(m, acc2[1][q][ri]);
                m = fmaxf(m, __shfl_xor(m, 16, 64));
                m = fmaxf(m, __shfl_xor(m, 32, 64));
                if (l < 16) {
                    int col = (w * 4 + q) * 16 + l;
                    sphb[col] = f2bf(fmaxf(BN_SF * (m + p.bm2[col]), 0.f));
                }
            }
        }
        __syncthreads();  // S4

        // ---- P4: di_next -> xf kc0..1 ; phw + dh1h -> dh1f ----
        for (int i = t; i < 2048; i += 1024) {
            int row = i >> 6, c = i & 63;
            float dv = srel[row * 2] * p.Wsp[c] + srel[row * 2 + 1] * p.Wsp[64 + c] + p.bsp[c];
            short hi = f2bf(dv);
            int off = (c >> 5) * 512 + ((row & 15) + (((c & 31) >> 3) << 4)) * 8 + (c & 7);
            XFH(row >> 4)[off] = hi; XFL(row >> 4)[off] = f2bf(dv - bf2f(hi));
        }
        {
            // phw (broadcast-A over Wd1p rows)
            float4v accp[4];
#pragma unroll
            for (int q = 0; q < 4; ++q) {
                int col = (w * 4 + q) * 16 + (l & 15);
                float bb = p.bd1[col];
                accp[q] = (float4v){bb, bb, bb, bb};
            }
#pragma unroll
            for (int kt = 0; kt < 16; ++kt) {
                short8v A[2], B[2][4];
#pragma unroll
                for (int kk = 0; kk < 2; ++kk) {
                    int kc = kt * 2 + kk;
#pragma unroll
                    for (int q = 0; q < 4; ++q)
                        B[kk][q] = *(const short8v*)(p.Wd1f + (size_t)(w * 4 + q) * 18432 + (size_t)(4 + kc) * 512 + l * 8);
                    A[kk] = *(const short8v*)(sphb + kc * 32 + ((l >> 4) << 3));
                }
#pragma unroll
                for (int kk = 0; kk < 2; ++kk)
#pragma unroll
                    for (int q = 0; q < 4; ++q)
                        accp[q] = __builtin_amdgcn_mfma_f32_16x16x32_bf16(A[kk], B[kk][q], accp[q], 0, 0, 0);
            }
            // dh1h
            float4v acch[4][2];
#pragma unroll
            for (int q = 0; q < 4; ++q) {
                acch[q][0] = (float4v){0.f, 0.f, 0.f, 0.f};
                acch[q][1] = (float4v){0.f, 0.f, 0.f, 0.f};
            }
#pragma unroll
            for (int kt = 0; kt < 2; ++kt) {
                short8v A0[2], A1[2], B[2][4];
#pragma unroll
                for (int kk = 0; kk < 2; ++kk) {
                    int kc = kt * 2 + kk;
#pragma unroll
                    for (int q = 0; q < 4; ++q)
                        B[kk][q] = *(const short8v*)(p.Wd1f + (size_t)(w * 4 + q) * 18432 + (size_t)kc * 512 + l * 8);
                    A0[kk] = *(const short8v*)(xmf + kc * 512 + l * 8);
                    A1[kk] = *(const short8v*)(xmf + 2048 + kc * 512 + l * 8);
                }
#pragma unroll
                for (int kk = 0; kk < 2; ++kk)
#pragma unroll
                    for (int q = 0; q < 4; ++q) {
                        acch[q][0] = __builtin_amdgcn_mfma_f32_16x16x32_bf16(A0[kk], B[kk][q], acch[q][0], 0, 0, 0);
                        acch[q][1] = __builtin_amdgcn_mfma_f32_16x16x32_bf16(A1[kk], B[kk][q], acch[q][1], 0, 0, 0);
                    }
            }
#pragma unroll
            for (int q = 0; q < 4; ++q) {
                int col = (w * 4 + q) * 16 + (l & 15);
                int kcD = col >> 5, jD = col & 7, lD = ((col & 31) >> 3) << 4;
#pragma unroll
                for (int m2i = 0; m2i < 2; ++m2i) {
#pragma unroll
                    for (int r = 0; r < 4; ++r) {
                        float v = fmaxf(BN_SF * (acch[q][m2i][r] + accp[q][r]), 0.f);
                        dh1f[m2i * 16384 + kcD * 512 + (rbase + r + lD) * 8 + jD] = f2bf(v);
                    }
                }
            }
        }
        __syncthreads();  // S5
    }

    // ---- epilogue: final h = relu(BN*(dh1 @ Wd2 + bd2)) -> out ----
    {
        float4v hacc = {0.f, 0.f, 0.f, 0.f};
        const short* ap = dh1f + mt * 16384 + l * 8;
        const short* bp = p.Wd2f + (size_t)w8 * 16384 + l * 8;
#pragma unroll
        for (int kt = 0; kt < 4; ++kt) {
            short8v B[8], A[8];
#pragma unroll
            for (int kk = 0; kk < 8; ++kk)
                B[kk] = *(const short8v*)(bp + (kt * 8 + kk) * 512);
#pragma unroll
            for (int kk = 0; kk < 8; ++kk)
                A[kk] = *(const short8v*)(ap + (kt * 8 + kk) * 512);
#pragma unroll
            for (int kk = 0; kk < 8; ++kk)
                hacc = __builtin_amdgcn_mfma_f32_16x16x32_bf16(A[kk], B[kk], hacc, 0, 0, 0);
        }
        float bb2 = p.bd2[colb];
#pragma unroll
        for (int r = 0; r < 4; ++r)
            p.out[24576 + (s * 32 + mt * 16 + rbase + r) * 128 + colb] =
                fmaxf(BN_SF * (hacc[r] + bb2), 0.f);
    }
#undef XFH
#undef XFL
#undef M1F
}

extern "C" void kernel_launch(void* const* d_in, const int* in_sizes, int n_in,
                              void* d_out, int out_size, void* d_ws, size_t ws_size,
                              hipStream_t stream) {
    float* ws = (float*)d_ws;
    float* uv   = ws;                       // 1024 f32
    short* sbase = (short*)(ws + 1024);
    short* Wm2s = sbase;                    // 524288
    short* Wd1f = Wm2s + 524288;            // 1179648
    short* Wd2f = Wd1f + 1179648;           // 131072
    short* Wm1f = Wd2f + 131072;            // 65536
    short* WgHi = Wm1f + 65536;             // 98304
    short* WgLo = WgHi + 98304;             // 98304

    SetupP sp;
    sp.Wm2  = (const float*)d_in[28];
    sp.Wd1  = (const float*)d_in[30];
    sp.Wd2  = (const float*)d_in[32];
    sp.Wm1  = (const float*)d_in[26];
    sp.Wih  = (const float*)d_in[10];
    sp.Whh  = (const float*)d_in[11];
    sp.Wpat = (const float*)d_in[20];
    sp.bpat = (const float*)d_in[21];
    sp.bm1  = (const float*)d_in[27];
    sp.Wm2s = Wm2s; sp.Wd1f = Wd1f; sp.Wd2f = Wd2f;
    sp.Wm1f = Wm1f; sp.WgHi = WgHi; sp.WgLo = WgLo;
    sp.uv = uv;

    MainP mp;
    mp.lpr  = (const float*)d_in[1];
    mp.h0   = (const float*)d_in[2];
    mp.c0   = (const float*)d_in[3];
    mp.at0  = (const float*)d_in[6];
    mp.Wsp  = (const float*)d_in[8];
    mp.bsp  = (const float*)d_in[9];
    mp.bih  = (const float*)d_in[12];
    mp.bhh  = (const float*)d_in[13];
    mp.Whp  = (const float*)d_in[14];
    mp.bhp  = (const float*)d_in[15];
    mp.bm2  = (const float*)d_in[29];
    mp.bd1  = (const float*)d_in[31];
    mp.bd2  = (const float*)d_in[33];
    mp.uv   = uv;
    mp.Wm2s = Wm2s; mp.Wd1f = Wd1f; mp.Wd2f = Wd2f;
    mp.Wm1f = Wm1f; mp.WgHi = WgHi; mp.WgLo = WgLo;
    mp.out  = (float*)d_out;

    k_setup<<<2048, 256, 0, stream>>>(sp);
    k_main<<<32, 1024, 0, stream>>>(mp);
}

// Round 8
// 427.576 us; speedup vs baseline: 4.6469x; 4.6469x over previous
//
#include <hip/hip_runtime.h>
#include <math.h>

#define BN_SF 0.9999950000374997f  /* 1/sqrt(1+1e-5) */

typedef __attribute__((ext_vector_type(8))) short short8v;
typedef __attribute__((ext_vector_type(4))) float float4v;

__device__ __forceinline__ float sigm(float x) { return 1.0f / (1.0f + expf(-x)); }

__device__ __forceinline__ short f2bf(float x) {
    unsigned u = __builtin_bit_cast(unsigned, x);
    unsigned r = (u + 0x7fffu + ((u >> 16) & 1u)) >> 16;
    return (short)r;
}
__device__ __forceinline__ float bf2f(short h) {
    unsigned u = ((unsigned)(unsigned short)h) << 16;
    return __builtin_bit_cast(float, u);
}

// f32 [K][N] row-major -> bf16 B-fragment layout for mfma_f32_16x16x32_bf16
template <int K, int N>
__device__ __forceinline__ void cvtB(const float* __restrict__ src, short* __restrict__ dst,
                                     float scale, int i) {
    int k = i / N, n = i % N;
    size_t d = (size_t)(n >> 4) * (K >> 5) * 512 + (size_t)(k >> 5) * 512
             + (size_t)(((n & 15) + (((k & 31) >> 3) << 4)) << 3) + (k & 7);
    dst[d] = f2bf(scale * src[i]);
}

struct SetupP {
    const float *Wm2, *Wd1, *Wd2, *Wm1, *Wih, *Whh, *Wpat, *bpat, *bm1;
    const float *lpr, *Wsp, *bsp, *c0;
    short *Wm2s, *Wd1f, *Wd2f, *Wm1f, *WgHi, *WgLo;
    float *uv, *di, *cbuf;
};

// ---- single setup kernel: all weight converts + uv + di0 + cbuf ----
__global__ __launch_bounds__(256) void k_setup(SetupP p) {
    int gt = blockIdx.x * 256 + threadIdx.x;
    int stride = gridDim.x * 256;
    for (int i = gt; i < 512 * 1024; i += stride)  cvtB<512, 1024>(p.Wm2, p.Wm2s, 1.f, i);
    for (int i = gt; i < 1152 * 1024; i += stride) cvtB<1152, 1024>(p.Wd1, p.Wd1f, 1.f, i);
    for (int i = gt; i < 1024 * 128; i += stride)  cvtB<1024, 128>(p.Wd2, p.Wd2f, 1.f, i);
    for (int i = gt; i < 128 * 512; i += stride)   cvtB<128, 512>(p.Wm1, p.Wm1f, 0.05f, i);
    for (int i = gt; i < 192 * 512; i += stride) {  // [W_ih;W_hh] hi/lo split
        int k = i >> 9, n = i & 511;
        float v = (k < 64) ? p.Wih[k * 512 + n] : p.Whh[(k - 64) * 512 + n];
        short hi = f2bf(v), lo = f2bf(v - bf2f(hi));
        size_t d = (size_t)(n >> 4) * 3072 + (size_t)(k >> 5) * 512
                 + (size_t)(((n & 15) + (((k & 31) >> 3) << 4)) << 3) + (k & 7);
        p.WgHi[d] = hi; p.WgLo[d] = lo;
    }
    for (int i = gt; i < 1024 * 64; i += stride) {  // di0
        int r = i >> 6, c = i & 63;
        p.di[i] = p.lpr[r * 2] * p.Wsp[c] + p.lpr[r * 2 + 1] * p.Wsp[64 + c] + p.bsp[c];
    }
    for (int i = gt; i < 1024 * 128; i += stride) p.cbuf[i] = p.c0[i];
    if (blockIdx.x == 0) {  // uv: rank-1 agent-type folding
        __shared__ float rw[64];
        int t = threadIdx.x;
        if (t < 64) { float s = 0.f; for (int k = 0; k < 6; ++k) s += p.Wpat[k * 64 + t]; rw[t] = s; }
        __syncthreads();
        for (int c = t; c < 512; c += 256) {
            float u = 0.f, v = 0.f;
            for (int e = 0; e < 64; ++e) {
                float wg = p.Wm1[(128 + e) * 512 + c];
                u += rw[e] * wg; v += p.bpat[e] * wg;
            }
            p.uv[c] = 0.05f * u; p.uv[512 + c] = 0.05f * v + p.bm1[c];
        }
    }
}

// ---- per step: dh2(prev, MFMA batched) + LSTM(hi/lo MFMA) + rel + di + m1 ----
// grid 64 blocks x 512 thr (8 waves); block b: 16 rows, scene b>>1, mt b&1
__global__ __launch_bounds__(512, 4) void k_step(
    const short* __restrict__ WgHi, const short* __restrict__ WgLo,
    const short* __restrict__ Wm1f, const short* __restrict__ Wd2f,
    const float* __restrict__ bih, const float* __restrict__ bhh,
    const float* __restrict__ Whp, const float* __restrict__ bhp,
    const float* __restrict__ Wsp, const float* __restrict__ bsp,
    const float* __restrict__ bd2, const float* __restrict__ at0,
    const float* __restrict__ uv, const float* __restrict__ h0,
    const short* __restrict__ dh1f, int first,
    float* __restrict__ cbuf, float* __restrict__ di,
    float* __restrict__ hA, short* __restrict__ m1s,
    float* __restrict__ outrel) {
    __shared__ float sh[16][128];
    __shared__ float sg[16][512];
    __shared__ float sdi[16][64];
    __shared__ short xfh[6 * 512];
    __shared__ short xfl[6 * 512];
    __shared__ short xm[4 * 512];
    __shared__ float sat[16];
    __shared__ float srel[16][2];
    int t = threadIdx.x, b = blockIdx.x;
    int l = t & 63, w = t >> 6;
    int r0 = b * 16;

    // dh2 MFMA (K=1024), batched 8 loads/round
    float4v hacc = {0.f, 0.f, 0.f, 0.f};
    if (!first) {
        const short* ap = dh1f + (size_t)b * 16384 + l * 8;
        const short* bp = Wd2f + (size_t)w * 16384 + l * 8;
#pragma unroll 1
        for (int kt = 0; kt < 4; ++kt) {
            short8v B[8], A[8];
#pragma unroll
            for (int kk = 0; kk < 8; ++kk) B[kk] = *(const short8v*)(bp + (kt * 8 + kk) * 512);
#pragma unroll
            for (int kk = 0; kk < 8; ++kk) A[kk] = *(const short8v*)(ap + (kt * 8 + kk) * 512);
#pragma unroll
            for (int kk = 0; kk < 8; ++kk)
                hacc = __builtin_amdgcn_mfma_f32_16x16x32_bf16(A[kk], B[kk], hacc, 0, 0, 0);
        }
    }
    for (int i = t; i < 16 * 64; i += 512) sdi[i >> 6][i & 63] = di[r0 * 64 + i];
    if (t < 16) sat[t] = at0[r0 + t];
    if (first) {
        for (int i = t; i < 16 * 128; i += 512) sh[i >> 7][i & 127] = h0[r0 * 128 + i];
    } else {
        int col = w * 16 + (l & 15);
        float bb2 = bd2[col];
#pragma unroll
        for (int r = 0; r < 4; ++r) {
            int row = ((l >> 4) << 2) + r;
            sh[row][col] = fmaxf(BN_SF * (hacc[r] + bb2), 0.f);
        }
    }
    __syncthreads();

    // X=[di|h] hi/lo A-fragments
    for (int i = t; i < 6 * 512; i += 512) {
        int pos = i & 511, kc = i >> 9;
        int ll = pos >> 3, j = pos & 7;
        int row = ll & 15, k = kc * 32 + ((ll >> 4) << 3) + j;
        float v = (k < 64) ? sdi[row][k] : sh[row][k - 64];
        short hi = f2bf(v);
        xfh[i] = hi;
        xfl[i] = f2bf(v - bf2f(hi));
    }
    __syncthreads();

    // gates MFMA (3 hi/lo terms), batched 2 kc/round
    {
        float4v ga[4] = {{0,0,0,0},{0,0,0,0},{0,0,0,0},{0,0,0,0}};
#pragma unroll 1
        for (int kt = 0; kt < 3; ++kt) {
            short8v BH[2][4], BL[2][4], AH[2], AL[2];
#pragma unroll
            for (int kk = 0; kk < 2; ++kk) {
                int kc = kt * 2 + kk;
#pragma unroll
                for (int q = 0; q < 4; ++q) {
                    int nf = w * 4 + q;
                    BH[kk][q] = *(const short8v*)(WgHi + (size_t)nf * 3072 + kc * 512 + l * 8);
                    BL[kk][q] = *(const short8v*)(WgLo + (size_t)nf * 3072 + kc * 512 + l * 8);
                }
                AH[kk] = *(const short8v*)(&xfh[kc * 512 + l * 8]);
                AL[kk] = *(const short8v*)(&xfl[kc * 512 + l * 8]);
            }
#pragma unroll
            for (int kk = 0; kk < 2; ++kk)
#pragma unroll
                for (int q = 0; q < 4; ++q) {
                    ga[q] = __builtin_amdgcn_mfma_f32_16x16x32_bf16(AH[kk], BH[kk][q], ga[q], 0, 0, 0);
                    ga[q] = __builtin_amdgcn_mfma_f32_16x16x32_bf16(AH[kk], BL[kk][q], ga[q], 0, 0, 0);
                    ga[q] = __builtin_amdgcn_mfma_f32_16x16x32_bf16(AL[kk], BH[kk][q], ga[q], 0, 0, 0);
                }
        }
#pragma unroll
        for (int q = 0; q < 4; ++q) {
            int col = (w * 4 + q) * 16 + (l & 15);
            float bb = bih[col] + bhh[col];
#pragma unroll
            for (int r = 0; r < 4; ++r) {
                int row = ((l >> 4) << 2) + r;
                sg[row][col] = ga[q][r] + bb;
            }
        }
    }
    __syncthreads();

    // LSTM pointwise (overwrites sh with new h)
    for (int i = t; i < 16 * 128; i += 512) {
        int row = i >> 7, j = i & 127;
        float gi = sg[row][j], gf = sg[row][j + 128], gg = sg[row][j + 256], go = sg[row][j + 384];
        float cn = sigm(gf) * cbuf[(r0 + row) * 128 + j] + sigm(gi) * tanhf(gg);
        float hn = sigm(go) * tanhf(cn);
        cbuf[(r0 + row) * 128 + j] = cn;
        sh[row][j] = hn;
        hA[(r0 + row) * 128 + j] = hn;
    }
    __syncthreads();

    // rel (f32, exact -> output)
    if (t < 32) {
        int row = t >> 1, d = t & 1;
        float s2 = bhp[d];
        for (int k = 0; k < 128; ++k) s2 += sh[row][k] * Whp[k * 2 + d];
        srel[row][d] = s2;
        outrel[(r0 + row) * 2 + d] = s2;
    }
    // new-h bf16 A-fragments for m1
    for (int i = t; i < 4 * 512; i += 512) {
        int pos = i & 511, kc = i >> 9;
        int ll = pos >> 3, j = pos & 7;
        int row = ll & 15, k = kc * 32 + ((ll >> 4) << 3) + j;
        xm[i] = f2bf(sh[row][k]);
    }
    __syncthreads();

    // di_next
    for (int i = t; i < 16 * 64; i += 512) {
        int row = i >> 6, c = i & 63;
        di[(r0 + row) * 64 + c] = srel[row][0] * Wsp[c] + srel[row][1] * Wsp[64 + c] + bsp[c];
    }

    // m1 MFMA (single batched group of 4 kc)
    {
        float4v ma[4] = {{0,0,0,0},{0,0,0,0},{0,0,0,0},{0,0,0,0}};
        short8v A[4], B[4][4];
#pragma unroll
        for (int kc = 0; kc < 4; ++kc) {
#pragma unroll
            for (int q = 0; q < 4; ++q)
                B[kc][q] = *(const short8v*)(Wm1f + (size_t)(w * 4 + q) * 2048 + kc * 512 + l * 8);
            A[kc] = *(const short8v*)(&xm[kc * 512 + l * 8]);
        }
#pragma unroll
        for (int kc = 0; kc < 4; ++kc)
#pragma unroll
            for (int q = 0; q < 4; ++q)
                ma[q] = __builtin_amdgcn_mfma_f32_16x16x32_bf16(A[kc], B[kc][q], ma[q], 0, 0, 0);
        int sS = b >> 1, mtS = b & 1;
#pragma unroll
        for (int q = 0; q < 4; ++q) {
            int col = (w * 4 + q) * 16 + (l & 15);
            float uc = uv[col], vc = uv[512 + col];
#pragma unroll
            for (int r = 0; r < 4; ++r) {
                int rowC = ((l >> 4) << 2) + r;
                float pre = ma[q][r] + sat[rowC] * uc + vc;
                float m1v = fmaxf(BN_SF * pre, 0.f);
                int kcD = col >> 5;
                int laneD = rowC + (((col & 31) >> 3) << 4);
                m1s[(size_t)sS * 16384 + kcD * 1024 + mtS * 512 + laneD * 8 + (col & 7)] = f2bf(m1v);
            }
        }
    }
}

// ---- per step: m2 = m1 @ Wm2 (MFMA batched), per-scene colmax -> ph ----
// grid 256 = 32 scenes x 8 colslices(128); 256 thr = 4 waves x 2 n-frags
__global__ __launch_bounds__(256, 4) void k_m2(const short* __restrict__ m1s,
                                               const short* __restrict__ Wm2s,
                                               const float* __restrict__ bm2,
                                               float* __restrict__ ph) {
    int t = threadIdx.x;
    int w = t >> 6, l = t & 63;
    int s = blockIdx.x >> 3, ct = blockIdx.x & 7;
    const short* ap = m1s + (size_t)s * 16384 + l * 8;
    const short* bp = Wm2s + (size_t)(ct * 8 + w * 2) * 8192 + l * 8;
    float4v acc[2][2] = {{{0,0,0,0},{0,0,0,0}},{{0,0,0,0},{0,0,0,0}}};
#pragma unroll 1
    for (int kt = 0; kt < 4; ++kt) {
        short8v A0[4], A1[4], B[4][2];
#pragma unroll
        for (int kk = 0; kk < 4; ++kk) {
            int kc = kt * 4 + kk;
#pragma unroll
            for (int q = 0; q < 2; ++q)
                B[kk][q] = *(const short8v*)(bp + q * 8192 + kc * 512);
            A0[kk] = *(const short8v*)(ap + kc * 1024);
            A1[kk] = *(const short8v*)(ap + kc * 1024 + 512);
        }
#pragma unroll
        for (int kk = 0; kk < 4; ++kk)
#pragma unroll
            for (int q = 0; q < 2; ++q) {
                acc[0][q] = __builtin_amdgcn_mfma_f32_16x16x32_bf16(A0[kk], B[kk][q], acc[0][q], 0, 0, 0);
                acc[1][q] = __builtin_amdgcn_mfma_f32_16x16x32_bf16(A1[kk], B[kk][q], acc[1][q], 0, 0, 0);
            }
    }
#pragma unroll
    for (int q = 0; q < 2; ++q) {
        float m = acc[0][q][0];
#pragma unroll
        for (int ri = 1; ri < 4; ++ri) m = fmaxf(m, acc[0][q][ri]);
#pragma unroll
        for (int ri = 0; ri < 4; ++ri) m = fmaxf(m, acc[1][q][ri]);
        m = fmaxf(m, __shfl_xor(m, 16, 64));
        m = fmaxf(m, __shfl_xor(m, 32, 64));
        if (l < 16) {
            int col = (ct * 8 + w * 2 + q) * 16 + l;
            ph[s * 1024 + col] = fmaxf(BN_SF * (m + bm2[col]), 0.f);
        }
    }
}

// ---- per step: phw (broadcast-A MFMA, batched) + dh1h MFMA -> dh1f frags ----
// grid 512 = 32 scenes x 16 colslices(64); 256 thr = 4 waves x 1 n-frag
__global__ __launch_bounds__(256, 4) void k_pool2(const short* __restrict__ Wd1f,
                                                  const float* __restrict__ bd1,
                                                  const float* __restrict__ ph,
                                                  const float* __restrict__ hA,
                                                  short* __restrict__ dh1f) {
    __shared__ short sphb[1024];
    __shared__ short shf[2][2048];
    int t = threadIdx.x, l = t & 63, w = t >> 6;
    int s = blockIdx.x >> 4, ct = blockIdx.x & 15;
    int nf = ct * 4 + w;
    for (int i = t; i < 1024; i += 256) sphb[i] = f2bf(ph[s * 1024 + i]);
    for (int i = t; i < 4096; i += 256) {
        int mt = i >> 11, pos = i & 2047;
        int kc = pos >> 9, ll = (pos >> 3) & 63, j = pos & 7;
        int row = ll & 15, k = kc * 32 + ((ll >> 4) << 3) + j;
        shf[mt][pos] = f2bf(hA[(s * 32 + mt * 16 + row) * 128 + k]);
    }
    __syncthreads();
    int col = nf * 16 + (l & 15);
    float bb0 = bd1[col];
    float4v accp = {bb0, bb0, bb0, bb0};
    const short* bpp = Wd1f + (size_t)nf * 18432 + l * 8;
#pragma unroll 1
    for (int kt = 0; kt < 8; ++kt) {
        short8v A[4], B[4];
#pragma unroll
        for (int kk = 0; kk < 4; ++kk) {
            int kc = kt * 4 + kk;
            B[kk] = *(const short8v*)(bpp + (size_t)(4 + kc) * 512);
            A[kk] = *(const short8v*)(&sphb[kc * 32 + ((l >> 4) << 3)]);
        }
#pragma unroll
        for (int kk = 0; kk < 4; ++kk)
            accp = __builtin_amdgcn_mfma_f32_16x16x32_bf16(A[kk], B[kk], accp, 0, 0, 0);
    }
    float4v acch[2] = {{0,0,0,0},{0,0,0,0}};
    {
        short8v A0[4], A1[4], B[4];
#pragma unroll
        for (int kc = 0; kc < 4; ++kc) {
            B[kc] = *(const short8v*)(bpp + (size_t)kc * 512);
            A0[kc] = *(const short8v*)(&shf[0][kc * 512 + l * 8]);
            A1[kc] = *(const short8v*)(&shf[1][kc * 512 + l * 8]);
        }
#pragma unroll
        for (int kc = 0; kc < 4; ++kc) {
            acch[0] = __builtin_amdgcn_mfma_f32_16x16x32_bf16(A0[kc], B[kc], acch[0], 0, 0, 0);
            acch[1] = __builtin_amdgcn_mfma_f32_16x16x32_bf16(A1[kc], B[kc], acch[1], 0, 0, 0);
        }
    }
    int rbase = (l >> 4) << 2;
    int kcD = col >> 5, jD = col & 7, lD = ((col & 31) >> 3) << 4;
#pragma unroll
    for (int m2i = 0; m2i < 2; ++m2i) {
#pragma unroll
        for (int r = 0; r < 4; ++r) {
            float v = fmaxf(BN_SF * (acch[m2i][r] + accp[r]), 0.f);
            dh1f[(size_t)(s * 2 + m2i) * 16384 + (size_t)kcD * 512 + (rbase + r + lD) * 8 + jD] = f2bf(v);
        }
    }
}

// ---- final: h = relu(BN*(dh1 @ Wd2 + bd2)) -> out (MFMA) ----
__global__ __launch_bounds__(512) void k_hfin2(const short* __restrict__ Wd2f,
                                               const float* __restrict__ bd2,
                                               const short* __restrict__ dh1f,
                                               float* __restrict__ outh) {
    int t = threadIdx.x, l = t & 63, w = t >> 6, b = blockIdx.x;
    float4v acc = {0.f, 0.f, 0.f, 0.f};
    const short* ap = dh1f + (size_t)b * 16384 + l * 8;
    const short* bp = Wd2f + (size_t)w * 16384 + l * 8;
#pragma unroll 1
    for (int kt = 0; kt < 4; ++kt) {
        short8v B[8], A[8];
#pragma unroll
        for (int kk = 0; kk < 8; ++kk) B[kk] = *(const short8v*)(bp + (kt * 8 + kk) * 512);
#pragma unroll
        for (int kk = 0; kk < 8; ++kk) A[kk] = *(const short8v*)(ap + (kt * 8 + kk) * 512);
#pragma unroll
        for (int kk = 0; kk < 8; ++kk)
            acc = __builtin_amdgcn_mfma_f32_16x16x32_bf16(A[kk], B[kk], acc, 0, 0, 0);
    }
    int col = w * 16 + (l & 15);
    float bb2 = bd2[col];
#pragma unroll
    for (int r = 0; r < 4; ++r) {
        int row = ((l >> 4) << 2) + r;
        outh[(b * 16 + row) * 128 + col] = fmaxf(BN_SF * (acc[r] + bb2), 0.f);
    }
}

extern "C" void kernel_launch(void* const* d_in, const int* in_sizes, int n_in,
                              void* d_out, int out_size, void* d_ws, size_t ws_size,
                              hipStream_t stream) {
    const float* last_pos_rel = (const float*)d_in[1];
    const float* h0           = (const float*)d_in[2];
    const float* c0           = (const float*)d_in[3];
    const float* agent_type   = (const float*)d_in[6];
    const float* W_sp  = (const float*)d_in[8];
    const float* b_sp  = (const float*)d_in[9];
    const float* W_ih  = (const float*)d_in[10];
    const float* W_hh  = (const float*)d_in[11];
    const float* b_ih  = (const float*)d_in[12];
    const float* b_hh  = (const float*)d_in[13];
    const float* W_h2p = (const float*)d_in[14];
    const float* b_h2p = (const float*)d_in[15];
    const float* Wp_at = (const float*)d_in[20];
    const float* bp_at = (const float*)d_in[21];
    const float* Wm1   = (const float*)d_in[26];
    const float* bm1   = (const float*)d_in[27];
    const float* Wm2   = (const float*)d_in[28];
    const float* bm2   = (const float*)d_in[29];
    const float* Wd1   = (const float*)d_in[30];
    const float* bd1   = (const float*)d_in[31];
    const float* Wd2   = (const float*)d_in[32];
    const float* bd2   = (const float*)d_in[33];
    float* out = (float*)d_out;

    float* ws   = (float*)d_ws;
    float* hA   = ws;              // 131072 f
    float* cbuf = hA + 131072;     // 131072 f
    float* di   = cbuf + 131072;   // 65536 f
    float* ph   = di + 65536;      // 32768 f
    float* uv   = ph + 32768;      // 1024 f
    short* m1s  = (short*)(uv + 1024);   // 524288 sh
    short* Wm2s = m1s + 524288;          // 524288 sh
    short* dh1f = Wm2s + 524288;         // 1048576 sh
    short* WgHi = dh1f + 1048576;        // 98304 sh
    short* WgLo = WgHi + 98304;          // 98304 sh
    short* Wm1f = WgLo + 98304;          // 65536 sh
    short* Wd1f = Wm1f + 65536;          // 1179648 sh
    short* Wd2f = Wd1f + 1179648;        // 131072 sh

    SetupP sp;
    sp.Wm2 = Wm2; sp.Wd1 = Wd1; sp.Wd2 = Wd2; sp.Wm1 = Wm1;
    sp.Wih = W_ih; sp.Whh = W_hh; sp.Wpat = Wp_at; sp.bpat = bp_at; sp.bm1 = bm1;
    sp.lpr = last_pos_rel; sp.Wsp = W_sp; sp.bsp = b_sp; sp.c0 = c0;
    sp.Wm2s = Wm2s; sp.Wd1f = Wd1f; sp.Wd2f = Wd2f;
    sp.Wm1f = Wm1f; sp.WgHi = WgHi; sp.WgLo = WgLo;
    sp.uv = uv; sp.di = di; sp.cbuf = cbuf;

    k_setup<<<1024, 256, 0, stream>>>(sp);

    for (int t = 0; t < 12; ++t) {
        k_step<<<64, 512, 0, stream>>>(WgHi, WgLo, Wm1f, Wd2f,
                                       b_ih, b_hh, W_h2p, b_h2p, W_sp, b_sp,
                                       bd2, agent_type, uv, h0, dh1f, (t == 0) ? 1 : 0,
                                       cbuf, di, hA, m1s, out + (size_t)t * 2048);
        k_m2<<<256, 256, 0, stream>>>(m1s, Wm2s, bm2, ph);
        k_pool2<<<512, 256, 0, stream>>>(Wd1f, bd1, ph, hA, dh1f);
    }
    k_hfin2<<<64, 512, 0, stream>>>(Wd2f, bd2, dh1f, out + 24576);
}

// Round 9
// 372.934 us; speedup vs baseline: 5.3277x; 1.1465x over previous
//
#include <hip/hip_runtime.h>
#include <math.h>

#define BN_SF 0.9999950000374997f  /* 1/sqrt(1+1e-5) */

typedef __attribute__((ext_vector_type(8))) short short8v;
typedef __attribute__((ext_vector_type(4))) float float4v;

__device__ __forceinline__ float sigm(float x) { return 1.0f / (1.0f + expf(-x)); }

__device__ __forceinline__ short f2bf(float x) {
    unsigned u = __builtin_bit_cast(unsigned, x);
    unsigned r = (u + 0x7fffu + ((u >> 16) & 1u)) >> 16;
    return (short)r;
}
__device__ __forceinline__ float bf2f(short h) {
    unsigned u = ((unsigned)(unsigned short)h) << 16;
    return __builtin_bit_cast(float, u);
}

// dst-linear B-fragment converter: thread g writes dst[8g..8g+7] (one short8).
// decode: ntg = g/((K/32)*64); kc = (g/64)%(K/32); lane = g%64
// n = ntg*16+(lane&15); k = kc*32+((lane>>4)<<3)+j
template <int K, int N>
__device__ __forceinline__ void cvtB8(const float* __restrict__ src, short* __restrict__ dst,
                                      float scale, int g) {
    const int KCN = K >> 5;
    int ntg = g / (KCN * 64);
    int rem = g - ntg * (KCN * 64);
    int kc = rem >> 6, lane = rem & 63;
    int n = ntg * 16 + (lane & 15);
    int k0 = kc * 32 + ((lane >> 4) << 3);
    short8v v;
#pragma unroll
    for (int j = 0; j < 8; ++j) v[j] = f2bf(scale * src[(size_t)(k0 + j) * N + n]);
    *(short8v*)(dst + (size_t)g * 8) = v;
}

struct SetupP {
    const float *Wm2, *Wd1, *Wd2, *Wm1, *Wih, *Whh, *Wpat, *bpat, *bm1;
    const float *lpr, *Wsp, *bsp, *c0;
    short *Wm2s, *Wd1f, *Wd2f, *Wm1f, *WgHi, *WgLo;
    float *uv, *di, *cbuf;
};

__global__ __launch_bounds__(256) void k_setup(SetupP p) {
    int gt = blockIdx.x * 256 + threadIdx.x;
    int stride = gridDim.x * 256;
    for (int g = gt; g < 512 * 1024 / 8; g += stride)  cvtB8<512, 1024>(p.Wm2, p.Wm2s, 1.f, g);
    for (int g = gt; g < 1152 * 1024 / 8; g += stride) cvtB8<1152, 1024>(p.Wd1, p.Wd1f, 1.f, g);
    for (int g = gt; g < 1024 * 128 / 8; g += stride)  cvtB8<1024, 128>(p.Wd2, p.Wd2f, 1.f, g);
    for (int g = gt; g < 128 * 512 / 8; g += stride)   cvtB8<128, 512>(p.Wm1, p.Wm1f, 0.05f, g);
    for (int g = gt; g < 192 * 512 / 8; g += stride) {  // [W_ih;W_hh] hi/lo split
        int ntg = g / (6 * 64);
        int rem = g - ntg * (6 * 64);
        int kc = rem >> 6, lane = rem & 63;
        int n = ntg * 16 + (lane & 15);
        int k0 = kc * 32 + ((lane >> 4) << 3);
        short8v vh, vl;
#pragma unroll
        for (int j = 0; j < 8; ++j) {
            int k = k0 + j;
            float v = (k < 64) ? p.Wih[(size_t)k * 512 + n] : p.Whh[(size_t)(k - 64) * 512 + n];
            short hi = f2bf(v);
            vh[j] = hi; vl[j] = f2bf(v - bf2f(hi));
        }
        *(short8v*)(p.WgHi + (size_t)g * 8) = vh;
        *(short8v*)(p.WgLo + (size_t)g * 8) = vl;
    }
    for (int i = gt; i < 1024 * 64; i += stride) {  // di0
        int r = i >> 6, c = i & 63;
        p.di[i] = p.lpr[r * 2] * p.Wsp[c] + p.lpr[r * 2 + 1] * p.Wsp[64 + c] + p.bsp[c];
    }
    for (int i = gt; i < 1024 * 128; i += stride) p.cbuf[i] = p.c0[i];
    if (blockIdx.x == 0) {  // uv: rank-1 agent-type folding
        __shared__ float rw[64];
        int t = threadIdx.x;
        if (t < 64) { float s = 0.f; for (int k = 0; k < 6; ++k) s += p.Wpat[k * 64 + t]; rw[t] = s; }
        __syncthreads();
        for (int c = t; c < 512; c += 256) {
            float u = 0.f, v = 0.f;
            for (int e = 0; e < 64; ++e) {
                float wg = p.Wm1[(128 + e) * 512 + c];
                u += rw[e] * wg; v += p.bpat[e] * wg;
            }
            p.uv[c] = 0.05f * u; p.uv[512 + c] = 0.05f * v + p.bm1[c];
        }
    }
}

// ---- per step: [dh1(prev) from hf+phwp -> dh2] + LSTM + rel + di + m1 ----
// grid 64 x 512 thr (8 waves); block b: scene s=b>>1, half mt=b&1, rows r0=b*16
__global__ __launch_bounds__(512, 4) void k_step(
    const short* __restrict__ WgHi, const short* __restrict__ WgLo,
    const short* __restrict__ Wm1f, const short* __restrict__ Wd2f,
    const short* __restrict__ Wd1f,
    const float* __restrict__ bih, const float* __restrict__ bhh,
    const float* __restrict__ Whp, const float* __restrict__ bhp,
    const float* __restrict__ Wsp, const float* __restrict__ bsp,
    const float* __restrict__ bd1, const float* __restrict__ bd2,
    const float* __restrict__ at0, const float* __restrict__ uv,
    const float* __restrict__ h0,
    const float* __restrict__ phwp, const short* __restrict__ hf_in, int first,
    float* __restrict__ cbuf, float* __restrict__ di,
    short* __restrict__ hf_out, short* __restrict__ m1s,
    float* __restrict__ outrel) {
    __shared__ float sgu[16 * 512];      // 32KB: dh1L (phases A/B) then sg (gates)
    __shared__ float sh[16][128];
    __shared__ float sdi[16][64];
    __shared__ float phws[1024];
    __shared__ short xfh[6 * 512];
    __shared__ short xfl[6 * 512];
    __shared__ short xm[4 * 512];
    __shared__ float sat[16];
    __shared__ float srel[16][2];
    short* dh1L = (short*)sgu;
    float* sg = sgu;

    int t = threadIdx.x, b = blockIdx.x;
    int l = t & 63, w = t >> 6;
    int s = b >> 1, mt = b & 1, r0 = b * 16;
    int rbase = (l >> 4) << 2;

    for (int i = t; i < 16 * 64; i += 512) sdi[i >> 6][i & 63] = di[r0 * 64 + i];
    if (t < 16) sat[t] = at0[r0 + t];

    if (first) {
        for (int i = t; i < 16 * 128; i += 512) sh[i >> 7][i & 127] = h0[r0 * 128 + i];
        __syncthreads();
    } else {
        // phase A: phw sum + dh1 = bnrelu(h@Wd1h + phw) -> dh1L (A-frags)
        for (int i = t; i < 1024; i += 512) {
            float v = bd1[i];
#pragma unroll
            for (int ct = 0; ct < 8; ++ct) v += phwp[(size_t)s * 8192 + ct * 1024 + i];
            phws[i] = v;
        }
        __syncthreads();
        short8v Ah[4];
#pragma unroll
        for (int kc = 0; kc < 4; ++kc)
            Ah[kc] = *(const short8v*)(hf_in + (size_t)b * 2048 + kc * 512 + l * 8);
#pragma unroll 1
        for (int q2 = 0; q2 < 4; ++q2) {
            short8v B[2][4];
#pragma unroll
            for (int qq = 0; qq < 2; ++qq)
#pragma unroll
                for (int kc = 0; kc < 4; ++kc)
                    B[qq][kc] = *(const short8v*)(Wd1f + (size_t)(w * 8 + q2 * 2 + qq) * 18432 + kc * 512 + l * 8);
            float4v acc2[2];
#pragma unroll
            for (int qq = 0; qq < 2; ++qq) {
                int col = (w * 8 + q2 * 2 + qq) * 16 + (l & 15);
                float pv = phws[col];
                acc2[qq] = (float4v){pv, pv, pv, pv};
            }
#pragma unroll
            for (int kc = 0; kc < 4; ++kc)
#pragma unroll
                for (int qq = 0; qq < 2; ++qq)
                    acc2[qq] = __builtin_amdgcn_mfma_f32_16x16x32_bf16(Ah[kc], B[qq][kc], acc2[qq], 0, 0, 0);
#pragma unroll
            for (int qq = 0; qq < 2; ++qq) {
                int col = (w * 8 + q2 * 2 + qq) * 16 + (l & 15);
                int kcD = col >> 5, jD = col & 7, lD = ((col & 31) >> 3) << 4;
#pragma unroll
                for (int r = 0; r < 4; ++r) {
                    float v = fmaxf(BN_SF * acc2[qq][r], 0.f);
                    dh1L[kcD * 512 + (rbase + r + lD) * 8 + jD] = f2bf(v);
                }
            }
        }
        __syncthreads();
        // phase B: dh2 (K=1024) -> h_in
        float4v hacc = {0.f, 0.f, 0.f, 0.f};
        const short* ap = dh1L + l * 8;
        const short* bp = Wd2f + (size_t)w * 16384 + l * 8;
#pragma unroll 1
        for (int kt = 0; kt < 4; ++kt) {
            short8v B[8], A[8];
#pragma unroll
            for (int kk = 0; kk < 8; ++kk) B[kk] = *(const short8v*)(bp + (kt * 8 + kk) * 512);
#pragma unroll
            for (int kk = 0; kk < 8; ++kk) A[kk] = *(const short8v*)(ap + (kt * 8 + kk) * 512);
#pragma unroll
            for (int kk = 0; kk < 8; ++kk)
                hacc = __builtin_amdgcn_mfma_f32_16x16x32_bf16(A[kk], B[kk], hacc, 0, 0, 0);
        }
        int col = w * 16 + (l & 15);
        float bb2 = bd2[col];
        __syncthreads();  // dh1L reads done; sh writes below race-free vs nothing
#pragma unroll
        for (int r = 0; r < 4; ++r)
            sh[rbase + r][col] = fmaxf(BN_SF * (hacc[r] + bb2), 0.f);
        __syncthreads();
    }

    // X=[di|h] hi/lo A-fragments
    for (int i = t; i < 6 * 512; i += 512) {
        int pos = i & 511, kc = i >> 9;
        int ll = pos >> 3, j = pos & 7;
        int row = ll & 15, k = kc * 32 + ((ll >> 4) << 3) + j;
        float v = (k < 64) ? sdi[row][k] : sh[row][k - 64];
        short hi = f2bf(v);
        xfh[i] = hi;
        xfl[i] = f2bf(v - bf2f(hi));
    }
    __syncthreads();

    // gates MFMA (3 hi/lo terms) -> sg (aliases dh1L, safe after sync)
    {
        float4v ga[4] = {{0,0,0,0},{0,0,0,0},{0,0,0,0},{0,0,0,0}};
#pragma unroll 1
        for (int kt = 0; kt < 3; ++kt) {
            short8v BH[2][4], BL[2][4], AH[2], AL[2];
#pragma unroll
            for (int kk = 0; kk < 2; ++kk) {
                int kc = kt * 2 + kk;
#pragma unroll
                for (int q = 0; q < 4; ++q) {
                    int nf = w * 4 + q;
                    BH[kk][q] = *(const short8v*)(WgHi + (size_t)nf * 3072 + kc * 512 + l * 8);
                    BL[kk][q] = *(const short8v*)(WgLo + (size_t)nf * 3072 + kc * 512 + l * 8);
                }
                AH[kk] = *(const short8v*)(&xfh[kc * 512 + l * 8]);
                AL[kk] = *(const short8v*)(&xfl[kc * 512 + l * 8]);
            }
#pragma unroll
            for (int kk = 0; kk < 2; ++kk)
#pragma unroll
                for (int q = 0; q < 4; ++q) {
                    ga[q] = __builtin_amdgcn_mfma_f32_16x16x32_bf16(AH[kk], BH[kk][q], ga[q], 0, 0, 0);
                    ga[q] = __builtin_amdgcn_mfma_f32_16x16x32_bf16(AH[kk], BL[kk][q], ga[q], 0, 0, 0);
                    ga[q] = __builtin_amdgcn_mfma_f32_16x16x32_bf16(AL[kk], BH[kk][q], ga[q], 0, 0, 0);
                }
        }
#pragma unroll
        for (int q = 0; q < 4; ++q) {
            int col = (w * 4 + q) * 16 + (l & 15);
            float bb = bih[col] + bhh[col];
#pragma unroll
            for (int r = 0; r < 4; ++r)
                sg[(rbase + r) * 512 + col] = ga[q][r] + bb;
        }
    }
    __syncthreads();

    // LSTM pointwise -> sh (new h), xm frags, hf_out
    for (int i = t; i < 16 * 128; i += 512) {
        int row = i >> 7, j = i & 127;
        float gi = sg[row * 512 + j], gf = sg[row * 512 + j + 128];
        float gg = sg[row * 512 + j + 256], go = sg[row * 512 + j + 384];
        float cn = sigm(gf) * cbuf[(r0 + row) * 128 + j] + sigm(gi) * tanhf(gg);
        float hn = sigm(go) * tanhf(cn);
        cbuf[(r0 + row) * 128 + j] = cn;
        sh[row][j] = hn;
    }
    __syncthreads();

    // rel (f32, exact -> output)
    if (t < 32) {
        int row = t >> 1, d = t & 1;
        float s2 = bhp[d];
        for (int k = 0; k < 128; ++k) s2 += sh[row][k] * Whp[k * 2 + d];
        srel[row][d] = s2;
        outrel[(r0 + row) * 2 + d] = s2;
    }
    // new-h bf16 A-fragments (LDS + global hf for next step's dh1)
    for (int i = t; i < 4 * 512; i += 512) {
        int pos = i & 511, kc = i >> 9;
        int ll = pos >> 3, j = pos & 7;
        int row = ll & 15, k = kc * 32 + ((ll >> 4) << 3) + j;
        short hv = f2bf(sh[row][k]);
        xm[i] = hv;
        hf_out[(size_t)b * 2048 + i] = hv;
    }
    __syncthreads();

    // di_next
    for (int i = t; i < 16 * 64; i += 512) {
        int row = i >> 6, c = i & 63;
        di[(r0 + row) * 64 + c] = srel[row][0] * Wsp[c] + srel[row][1] * Wsp[64 + c] + bsp[c];
    }

    // m1 MFMA -> m1s (A-frag layout for k_m2)
    {
        float4v ma[4] = {{0,0,0,0},{0,0,0,0},{0,0,0,0},{0,0,0,0}};
        short8v A[4], B[4][4];
#pragma unroll
        for (int kc = 0; kc < 4; ++kc) {
#pragma unroll
            for (int q = 0; q < 4; ++q)
                B[kc][q] = *(const short8v*)(Wm1f + (size_t)(w * 4 + q) * 2048 + kc * 512 + l * 8);
            A[kc] = *(const short8v*)(&xm[kc * 512 + l * 8]);
        }
#pragma unroll
        for (int kc = 0; kc < 4; ++kc)
#pragma unroll
            for (int q = 0; q < 4; ++q)
                ma[q] = __builtin_amdgcn_mfma_f32_16x16x32_bf16(A[kc], B[kc][q], ma[q], 0, 0, 0);
#pragma unroll
        for (int q = 0; q < 4; ++q) {
            int col = (w * 4 + q) * 16 + (l & 15);
            float uc = uv[col], vc = uv[512 + col];
#pragma unroll
            for (int r = 0; r < 4; ++r) {
                int rowC = rbase + r;
                float m1v = fmaxf(BN_SF * (ma[q][r] + sat[rowC] * uc + vc), 0.f);
                int kcD = col >> 5;
                int laneD = rowC + (((col & 31) >> 3) << 4);
                m1s[(size_t)s * 16384 + kcD * 1024 + mt * 512 + laneD * 8 + (col & 7)] = f2bf(m1v);
            }
        }
    }
}

// ---- per step: m2 (MFMA) + colmax -> ph slice -> partial phw (K-split) ----
// grid 256 = 32 scenes x 8 K/col-slices; 512 thr = 8 waves
__global__ __launch_bounds__(512, 4) void k_m2(const short* __restrict__ m1s,
                                               const short* __restrict__ Wm2s,
                                               const short* __restrict__ Wd1f,
                                               const float* __restrict__ bm2,
                                               float* __restrict__ phwp) {
    __shared__ short sphb[128];
    int t = threadIdx.x, l = t & 63, w = t >> 6;
    int s = blockIdx.x >> 3, ct = blockIdx.x & 7;

    // m2: wave w -> output n-frag nf = ct*8+w; both m-tiles
    {
        int nf = ct * 8 + w;
        const short* ap = m1s + (size_t)s * 16384 + l * 8;
        const short* bp = Wm2s + (size_t)nf * 8192 + l * 8;
        float4v acc0 = {0,0,0,0}, acc1 = {0,0,0,0};
#pragma unroll 1
        for (int kt = 0; kt < 4; ++kt) {
            short8v A0[4], A1[4], B[4];
#pragma unroll
            for (int kk = 0; kk < 4; ++kk) {
                int kc = kt * 4 + kk;
                B[kk] = *(const short8v*)(bp + kc * 512);
                A0[kk] = *(const short8v*)(ap + kc * 1024);
                A1[kk] = *(const short8v*)(ap + kc * 1024 + 512);
            }
#pragma unroll
            for (int kk = 0; kk < 4; ++kk) {
                acc0 = __builtin_amdgcn_mfma_f32_16x16x32_bf16(A0[kk], B[kk], acc0, 0, 0, 0);
                acc1 = __builtin_amdgcn_mfma_f32_16x16x32_bf16(A1[kk], B[kk], acc1, 0, 0, 0);
            }
        }
        float m = acc0[0];
#pragma unroll
        for (int ri = 1; ri < 4; ++ri) m = fmaxf(m, acc0[ri]);
#pragma unroll
        for (int ri = 0; ri < 4; ++ri) m = fmaxf(m, acc1[ri]);
        m = fmaxf(m, __shfl_xor(m, 16, 64));
        m = fmaxf(m, __shfl_xor(m, 32, 64));
        if (l < 16) {
            int col = nf * 16 + l;
            sphb[w * 16 + l] = f2bf(fmaxf(BN_SF * (m + bm2[col]), 0.f));
        }
    }
    __syncthreads();

    // partial phw: ph-slice(128) @ Wd1p[ct*128.., all 1024 cols], broadcast-A
    {
        short8v Ap[4];
#pragma unroll
        for (int kk = 0; kk < 4; ++kk)
            Ap[kk] = *(const short8v*)(sphb + kk * 32 + ((l >> 4) << 3));
#pragma unroll 1
        for (int q2 = 0; q2 < 4; ++q2) {
            short8v B[2][4];
#pragma unroll
            for (int qq = 0; qq < 2; ++qq)
#pragma unroll
                for (int kk = 0; kk < 4; ++kk)
                    B[qq][kk] = *(const short8v*)(Wd1f + (size_t)(w * 8 + q2 * 2 + qq) * 18432
                                                  + (size_t)(4 + ct * 4 + kk) * 512 + l * 8);
            float4v acc2[2] = {{0,0,0,0},{0,0,0,0}};
#pragma unroll
            for (int kk = 0; kk < 4; ++kk)
#pragma unroll
                for (int qq = 0; qq < 2; ++qq)
                    acc2[qq] = __builtin_amdgcn_mfma_f32_16x16x32_bf16(Ap[kk], B[qq][kk], acc2[qq], 0, 0, 0);
            if (l < 16) {
#pragma unroll
                for (int qq = 0; qq < 2; ++qq) {
                    int nf_p = w * 8 + q2 * 2 + qq;
                    phwp[(size_t)s * 8192 + ct * 1024 + nf_p * 16 + l] = acc2[qq][0];
                }
            }
        }
    }
}

// ---- final: dh1(12) from hf+phwp, dh2 -> out h ----
__global__ __launch_bounds__(512, 4) void k_hfin(const short* __restrict__ Wd2f,
                                                 const short* __restrict__ Wd1f,
                                                 const float* __restrict__ bd1,
                                                 const float* __restrict__ bd2,
                                                 const float* __restrict__ phwp,
                                                 const short* __restrict__ hf,
                                                 float* __restrict__ outh) {
    __shared__ float phws[1024];
    __shared__ short dh1L[16384];
    int t = threadIdx.x, b = blockIdx.x;
    int l = t & 63, w = t >> 6;
    int s = b >> 1, rbase = (l >> 4) << 2;

    for (int i = t; i < 1024; i += 512) {
        float v = bd1[i];
#pragma unroll
        for (int ct = 0; ct < 8; ++ct) v += phwp[(size_t)s * 8192 + ct * 1024 + i];
        phws[i] = v;
    }
    __syncthreads();
    short8v Ah[4];
#pragma unroll
    for (int kc = 0; kc < 4; ++kc)
        Ah[kc] = *(const short8v*)(hf + (size_t)b * 2048 + kc * 512 + l * 8);
#pragma unroll 1
    for (int q2 = 0; q2 < 4; ++q2) {
        short8v B[2][4];
#pragma unroll
        for (int qq = 0; qq < 2; ++qq)
#pragma unroll
            for (int kc = 0; kc < 4; ++kc)
                B[qq][kc] = *(const short8v*)(Wd1f + (size_t)(w * 8 + q2 * 2 + qq) * 18432 + kc * 512 + l * 8);
        float4v acc2[2];
#pragma unroll
        for (int qq = 0; qq < 2; ++qq) {
            int col = (w * 8 + q2 * 2 + qq) * 16 + (l & 15);
            float pv = phws[col];
            acc2[qq] = (float4v){pv, pv, pv, pv};
        }
#pragma unroll
        for (int kc = 0; kc < 4; ++kc)
#pragma unroll
            for (int qq = 0; qq < 2; ++qq)
                acc2[qq] = __builtin_amdgcn_mfma_f32_16x16x32_bf16(Ah[kc], B[qq][kc], acc2[qq], 0, 0, 0);
#pragma unroll
        for (int qq = 0; qq < 2; ++qq) {
            int col = (w * 8 + q2 * 2 + qq) * 16 + (l & 15);
            int kcD = col >> 5, jD = col & 7, lD = ((col & 31) >> 3) << 4;
#pragma unroll
            for (int r = 0; r < 4; ++r) {
                float v = fmaxf(BN_SF * acc2[qq][r], 0.f);
                dh1L[kcD * 512 + (rbase + r + lD) * 8 + jD] = f2bf(v);
            }
        }
    }
    __syncthreads();
    float4v hacc = {0.f, 0.f, 0.f, 0.f};
    const short* ap = dh1L + l * 8;
    const short* bp = Wd2f + (size_t)w * 16384 + l * 8;
#pragma unroll 1
    for (int kt = 0; kt < 4; ++kt) {
        short8v B[8], A[8];
#pragma unroll
        for (int kk = 0; kk < 8; ++kk) B[kk] = *(const short8v*)(bp + (kt * 8 + kk) * 512);
#pragma unroll
        for (int kk = 0; kk < 8; ++kk) A[kk] = *(const short8v*)(ap + (kt * 8 + kk) * 512);
#pragma unroll
        for (int kk = 0; kk < 8; ++kk)
            hacc = __builtin_amdgcn_mfma_f32_16x16x32_bf16(A[kk], B[kk], hacc, 0, 0, 0);
    }
    int col = w * 16 + (l & 15);
    float bb2 = bd2[col];
#pragma unroll
    for (int r = 0; r < 4; ++r)
        outh[(b * 16 + rbase + r) * 128 + col] = fmaxf(BN_SF * (hacc[r] + bb2), 0.f);
}

extern "C" void kernel_launch(void* const* d_in, const int* in_sizes, int n_in,
                              void* d_out, int out_size, void* d_ws, size_t ws_size,
                              hipStream_t stream) {
    const float* last_pos_rel = (const float*)d_in[1];
    const float* h0           = (const float*)d_in[2];
    const float* c0           = (const float*)d_in[3];
    const float* agent_type   = (const float*)d_in[6];
    const float* W_sp  = (const float*)d_in[8];
    const float* b_sp  = (const float*)d_in[9];
    const float* W_ih  = (const float*)d_in[10];
    const float* W_hh  = (const float*)d_in[11];
    const float* b_ih  = (const float*)d_in[12];
    const float* b_hh  = (const float*)d_in[13];
    const float* W_h2p = (const float*)d_in[14];
    const float* b_h2p = (const float*)d_in[15];
    const float* Wp_at = (const float*)d_in[20];
    const float* bp_at = (const float*)d_in[21];
    const float* Wm1   = (const float*)d_in[26];
    const float* bm1   = (const float*)d_in[27];
    const float* Wm2   = (const float*)d_in[28];
    const float* bm2   = (const float*)d_in[29];
    const float* Wd1   = (const float*)d_in[30];
    const float* bd1   = (const float*)d_in[31];
    const float* Wd2   = (const float*)d_in[32];
    const float* bd2   = (const float*)d_in[33];
    float* out = (float*)d_out;

    float* ws   = (float*)d_ws;
    float* uv   = ws;                  // 1024 f
    float* di   = uv + 1024;           // 65536 f
    float* cbuf = di + 65536;          // 131072 f
    float* phwp = cbuf + 131072;       // 262144 f (32 scenes x 8 x 1024)
    short* hf   = (short*)(phwp + 262144);  // 131072 sh (64 blocks x 2048)
    short* m1s  = hf + 131072;         // 524288 sh
    short* Wm2s = m1s + 524288;        // 524288 sh
    short* Wd1f = Wm2s + 524288;       // 1179648 sh
    short* Wd2f = Wd1f + 1179648;      // 131072 sh
    short* Wm1f = Wd2f + 131072;       // 65536 sh
    short* WgHi = Wm1f + 65536;        // 98304 sh
    short* WgLo = WgHi + 98304;        // 98304 sh

    SetupP sp;
    sp.Wm2 = Wm2; sp.Wd1 = Wd1; sp.Wd2 = Wd2; sp.Wm1 = Wm1;
    sp.Wih = W_ih; sp.Whh = W_hh; sp.Wpat = Wp_at; sp.bpat = bp_at; sp.bm1 = bm1;
    sp.lpr = last_pos_rel; sp.Wsp = W_sp; sp.bsp = b_sp; sp.c0 = c0;
    sp.Wm2s = Wm2s; sp.Wd1f = Wd1f; sp.Wd2f = Wd2f;
    sp.Wm1f = Wm1f; sp.WgHi = WgHi; sp.WgLo = WgLo;
    sp.uv = uv; sp.di = di; sp.cbuf = cbuf;

    k_setup<<<2048, 256, 0, stream>>>(sp);

    for (int t = 0; t < 12; ++t) {
        k_step<<<64, 512, 0, stream>>>(WgHi, WgLo, Wm1f, Wd2f, Wd1f,
                                       b_ih, b_hh, W_h2p, b_h2p, W_sp, b_sp,
                                       bd1, bd2, agent_type, uv, h0,
                                       phwp, hf, (t == 0) ? 1 : 0,
                                       cbuf, di, hf, m1s, out + (size_t)t * 2048);
        k_m2<<<256, 512, 0, stream>>>(m1s, Wm2s, Wd1f, bm2, phwp);
    }
    k_hfin<<<64, 512, 0, stream>>>(Wd2f, Wd1f, bd1, bd2, phwp, hf, out + 24576);
}